// Round 9
// baseline (562.429 us; speedup 1.0000x reference)
//
#include <hip/hip_runtime.h>

#define NN 8192
#define STEPS 64
#define DECAYF 0.9f
#define THRESHF 1.0f
#define K_MAX 384            // ELL row capacity = 2 segments x 192
#define K_SEG 192            // per-half-row segment (nnz ~129 +/- 11, +5.6 sigma)
#define KITER 24             // 384 / 16 lanes per row
#define LROWS 32             // rows per block
#define LPITCH 385           // LDS ELL row pitch in u64 (+1 pad: bank spread)

#define CBLOCKS 256          // one block per CU; regular launch
#define STHREADS 576         // 9 waves: wave 0 = poller, 1..8 compute+publish
#define MBSTRIDE 512         // u64 per mailbox entry = 4 KB: one L3 interleave
                             // granule per word (R22). History: stride 1 (4KB
                             // total = 1 granule) catastrophic (R15, +48us);
                             // stride 16 (8 granules) = 3.1us/step == model's
                             // 65536 reqs / 8 slices. 256 granules -> ~256
                             // reqs/slice/round -> poll service off the path.

typedef unsigned long long u64;
typedef unsigned int u32;

// R22: slice-spread mailbox. Step-phase model: per poll round the device
// issues 256 pollers x 256 words = 65536 L3 reads; they serialize on the
// L3 slices covering the mailbox's interleave granules. At 128-B stride
// the mailbox spans ~8 x 4KB granules -> ~8192 req/slice/round ~ 3.4us,
// matching the measured 3.1us/step. 4-KB stride gives every word its own
// granule -> full-slice spread. Single-parameter change on R21 (fused
// extraction + batched-ballot compaction + R13 poller/steps).
__device__ __forceinline__ void pub_store(u64* p, u64 v) {
    __hip_atomic_store(p, v, __ATOMIC_RELAXED, __HIP_MEMORY_SCOPE_AGENT);
}
__device__ __forceinline__ u64 pub_load(const u64* p) {
    return __hip_atomic_load(p, __ATOMIC_RELAXED, __HIP_MEMORY_SCOPE_AGENT);
}

__global__ __launch_bounds__(STHREADS) void spiking_fused(
        const float* __restrict__ W,
        const float* __restrict__ f0,
        const float* __restrict__ v0,
        float* __restrict__ out,
        u64* __restrict__ fdata) {       // [2][CBLOCKS][MBSTRIDE]
    __shared__ u64 lds_ell[LROWS * LPITCH];  // 98.5 KB packed ELL, this block
    __shared__ u32 lds_fbits[2][CBLOCKS];    // 2 KB, dbuf by parity
    __shared__ u32 lds_spike[8];             // bits4 per compute wave
    __shared__ int lds_cnt[STEPS];           // per-step arrive counters
    __shared__ int lds_flag;                 // monotonic: inputs ready

    const int tid  = threadIdx.x;
    const int wave = tid >> 6;
    const int lane = tid & 63;
    const int bid  = blockIdx.x;

    if (tid < STEPS) lds_cnt[tid] = 0;
    if (tid == 0) lds_flag = 0;

    // publish own f0 word (tag 1, slot 0) ASAP — lands while we extract
    if (wave == 0) {
        float f = (lane < 32) ? f0[bid * 32 + lane] : 0.0f;
        u64 m = __ballot(f != 0.0f);
        if (lane == 0)
            pub_store(&fdata[(size_t)bid * MBSTRIDE],
                      (1ull << 32) | (u32)(m & 0xffffffffull));
    }

    // ===== Phase 0: all 9 waves extract this block's 32 rows -> LDS ELL ====
    // 64 half-rows / 9 waves; half-row = 4096 cols = 16 float4/lane.
    {
        const u64 lmask = (1ull << lane) - 1ull;
        for (int hr = wave; hr < 2 * LROWS; hr += 9) {
            const int rloc = hr >> 1;
            const int half = hr & 1;
            const int cbase = half * (NN / 2);
            const float4* wr4 = (const float4*)
                (W + (size_t)(bid * LROWS + rloc) * NN + cbase);
            u64* pr = lds_ell + rloc * LPITCH + half * K_SEG;

            float4 wv[16];
            #pragma unroll
            for (int i = 0; i < 16; ++i)
                wv[i] = wr4[lane + 64 * i];

            int base = 0;
            #pragma unroll
            for (int i = 0; i < 16; ++i) {
                const int col0 = cbase + (lane + 64 * i) * 4;
                const float4 w = wv[i];
                // 4 independent ballots (no serial chain between them)
                u64 m0 = __ballot(w.x != 0.0f);
                u64 m1 = __ballot(w.y != 0.0f);
                u64 m2 = __ballot(w.z != 0.0f);
                u64 m3 = __ballot(w.w != 0.0f);
                int p0 = __popcll(m0), p1 = __popcll(m1),
                    p2 = __popcll(m2), p3 = __popcll(m3);
                int i0 = base + __popcll(m0 & lmask);
                int i1 = base + p0 + __popcll(m1 & lmask);
                int i2 = base + p0 + p1 + __popcll(m2 & lmask);
                int i3 = base + p0 + p1 + p2 + __popcll(m3 & lmask);
                if (w.x != 0.0f && i0 < K_SEG)       // +5.6 sigma guard
                    pr[i0] = ((u64)(u32)(col0 + 0) << 32)
                           | (u64)__float_as_uint(w.x);
                if (w.y != 0.0f && i1 < K_SEG)
                    pr[i1] = ((u64)(u32)(col0 + 1) << 32)
                           | (u64)__float_as_uint(w.y);
                if (w.z != 0.0f && i2 < K_SEG)
                    pr[i2] = ((u64)(u32)(col0 + 2) << 32)
                           | (u64)__float_as_uint(w.z);
                if (w.w != 0.0f && i3 < K_SEG)
                    pr[i3] = ((u64)(u32)(col0 + 3) << 32)
                           | (u64)__float_as_uint(w.w);
                base += p0 + p1 + p2 + p3;           // ONE serial update/float4
            }
            const int cap = (base < K_SEG) ? base : K_SEG;
            for (int j = cap + lane; j < K_SEG; j += 64) pr[j] = 0ull;
        }
    }
    __syncthreads();   // only barrier: ELL + control vars ready

    if (wave == 0) {
        // ===== PURE POLLER (R13 verbatim): fresh-check, stash, backoff =====
        for (int s = 0; s < STEPS; ++s) {
            const u64* slot = fdata + (size_t)(s & 1) * CBLOCKS * MBSTRIDE;
            const u32 want = (u32)(s + 1);
            u32* fb = lds_fbits[s & 1];
            u32 pend = 0xFu;                 // 4 words per lane outstanding
            for (;;) {
                #pragma unroll
                for (int k = 0; k < 4; ++k) {
                    if ((pend >> k) & 1u) {
                        u64 w = pub_load(&slot[(size_t)(lane + 64 * k) * MBSTRIDE]);
                        if ((u32)(w >> 32) == want) {
                            fb[lane + 64 * k] = (u32)w;   // stash on arrival
                            pend &= ~(1u << k);
                        }
                    }
                }
                if (__all(pend == 0)) break;
                __builtin_amdgcn_s_sleep(2);   // ~128 cyc: cut L3 read pressure
            }
            if (lane == 0)
                __hip_atomic_store(&lds_flag, s + 1, __ATOMIC_RELEASE,
                                   __HIP_MEMORY_SCOPE_WORKGROUP);
        }
    } else {
        // ===== COMPUTE (waves 1..8, 4 rows each); last wave publishes =====
        const int g    = wave - 1;               // 0..7
        const int rloc = g * 4 + (lane >> 4);    // local row 0..31
        const int row  = bid * LROWS + rloc;
        const int l16  = lane & 15;

        // one-time LDS ELL -> registers
        u32 ecol[KITER]; float eval[KITER];
        const u64* pr = lds_ell + rloc * LPITCH;
        #pragma unroll
        for (int k = 0; k < KITER; ++k) {
            u64 p = pr[l16 + 16 * k];
            ecol[k] = (u32)(p >> 32);
            eval[k] = __uint_as_float((u32)p);
        }
        float vreg = v0[row];                    // identical across the 16 lanes

        for (int s = 0; s < STEPS; ++s) {
            while (__hip_atomic_load(&lds_flag, __ATOMIC_ACQUIRE,
                                     __HIP_MEMORY_SCOPE_WORKGROUP) < s + 1) {}
            const u32* fb = lds_fbits[s & 1];

            // gather with 3 independent fp64 accumulators (short dep chains)
            double a0 = 0.0, a1 = 0.0, a2 = 0.0;
            #pragma unroll
            for (int k = 0; k < KITER; k += 3) {
                u32 c0 = ecol[k],     w0 = fb[c0 >> 5];
                u32 c1 = ecol[k + 1], w1 = fb[c1 >> 5];
                u32 c2 = ecol[k + 2], w2 = fb[c2 >> 5];
                a0 += (double)(((w0 >> (c0 & 31)) & 1u) ? eval[k]     : 0.0f);
                a1 += (double)(((w1 >> (c1 & 31)) & 1u) ? eval[k + 1] : 0.0f);
                a2 += (double)(((w2 >> (c2 & 31)) & 1u) ? eval[k + 2] : 0.0f);
            }
            double acc = (a0 + a1) + a2;
            #pragma unroll
            for (int m = 8; m >= 1; m >>= 1)     // 16-lane butterfly
                acc += __shfl_xor(acc, m, 64);

            float u  = (float)acc;
            float vv = __fadd_rn(__fmul_rn(DECAYF, vreg), u);
            int fire = (vv >= THRESHF);
            vreg = fire ? 0.0f : vv;

            // ---- publish path FIRST (critical chain), out[] store after ----
            u64 bal = __ballot(fire);            // uniform within 16-lane groups
            int old = -1;
            if (lane == 0) {
                u32 bits4 = ((u32)(bal       ) & 1u)
                          | (((u32)(bal >> 16) & 1u) << 1)
                          | (((u32)(bal >> 32) & 1u) << 2)
                          | (((u32)(bal >> 48) & 1u) << 3);
                __hip_atomic_store(&lds_spike[g], bits4, __ATOMIC_RELAXED,
                                   __HIP_MEMORY_SCOPE_WORKGROUP);
                old = __hip_atomic_fetch_add(&lds_cnt[s], 1, __ATOMIC_ACQ_REL,
                                             __HIP_MEMORY_SCOPE_WORKGROUP);
            }
            old = __shfl(old, 0, 64);
            if (old == 7) {                      // 8th (last) compute wave
                u32 b = (lane < 8) ? ((lds_spike[lane] & 0xFu) << (4 * lane)) : 0u;
                b |= __shfl_xor(b, 1, 64);
                b |= __shfl_xor(b, 2, 64);
                b |= __shfl_xor(b, 4, 64);
                if (lane == 0)
                    pub_store(&fdata[((size_t)((s + 1) & 1) * CBLOCKS + bid) * MBSTRIDE],
                              ((u64)(u32)(s + 2) << 32) | b);
            }

            if (l16 == 0)
                out[(size_t)s * NN + row] = fire ? 1.0f : 0.0f;
        }
    }
}

extern "C" void kernel_launch(void* const* d_in, const int* in_sizes, int n_in,
                              void* d_out, int out_size, void* d_ws, size_t ws_size,
                              hipStream_t stream) {
    const float* W  = (const float*)d_in[0];
    const float* f0 = (const float*)d_in[1];
    const float* v0 = (const float*)d_in[2];
    float* out = (float*)d_out;

    // workspace: slice-spread mailbox (2 MB); 0xAA poison != any tag 1..66
    u64* fdata = (u64*)d_ws;

    spiking_fused<<<dim3(CBLOCKS), dim3(STHREADS), 0, stream>>>(
        W, f0, v0, out, fdata);
}

// Round 10
// 559.967 us; speedup vs baseline: 1.0044x; 1.0044x over previous
//
#include <hip/hip_runtime.h>

#define NN 8192
#define STEPS 64
#define DECAYF 0.9f
#define THRESHF 1.0f
#define K_MAX 384            // ELL row capacity = 2 segments x 192
#define K_SEG 192            // per-half-row segment (nnz ~129 +/- 11, +5.6 sigma)
#define KITER 24             // 384 / 16 lanes per row
#define LROWS 32             // rows per block
#define LPITCH 385           // LDS ELL row pitch in u64 (+1 pad: bank spread)

#define CBLOCKS 256          // one block per CU; regular launch
#define STHREADS 1024        // 16 waves: 0=poller, 1..8 compute, 1..15 extract
#define XWAVES 15            // extraction waves (1..15); 9..15 exit after
#define MBSTRIDE 16          // u64 per mailbox entry = 128 B (best measured;
                             // stride 1 and 512 both regressed/null)

typedef unsigned long long u64;
typedef unsigned int u32;

// R23: max-wave extraction + barrier decoupling. 6 extraction-mechanism
// variants were null; the one axis never varied in the fused kernel is
// per-wave serial work (9 waves x 7.1 half-rows). Now 15 waves x 4.27
// half-rows; waves 9-15 are extraction-only helpers that exit before the
// step phase (proven 9-wave step topology untouched). The post-extraction
// __syncthreads is replaced by an LDS release/acquire counter (wave 0
// would deadlock in its poll loop): ONE top barrier for init visibility,
// then wave 0 polls IMMEDIATELY -> f0 stash overlaps extraction, step-0
// detect leaves the critical path. Poller + step loop: R13-verbatim.
__device__ __forceinline__ void pub_store(u64* p, u64 v) {
    __hip_atomic_store(p, v, __ATOMIC_RELAXED, __HIP_MEMORY_SCOPE_AGENT);
}
__device__ __forceinline__ u64 pub_load(const u64* p) {
    return __hip_atomic_load(p, __ATOMIC_RELAXED, __HIP_MEMORY_SCOPE_AGENT);
}

__global__ __launch_bounds__(STHREADS) void spiking_fused(
        const float* __restrict__ W,
        const float* __restrict__ f0,
        const float* __restrict__ v0,
        float* __restrict__ out,
        u64* __restrict__ fdata) {       // [2][CBLOCKS][MBSTRIDE]
    __shared__ u64 lds_ell[LROWS * LPITCH];  // 98.5 KB packed ELL, this block
    __shared__ u32 lds_fbits[2][CBLOCKS];    // 2 KB, dbuf by parity
    __shared__ u32 lds_spike[8];             // bits4 per compute wave
    __shared__ int lds_cnt[STEPS];           // per-step arrive counters
    __shared__ int lds_flag;                 // monotonic: inputs ready
    __shared__ int lds_ext;                  // extraction-done counter

    const int tid  = threadIdx.x;
    const int wave = tid >> 6;
    const int lane = tid & 63;
    const int bid  = blockIdx.x;

    if (tid < STEPS) lds_cnt[tid] = 0;
    if (tid == 0) { lds_flag = 0; lds_ext = 0; }
    __syncthreads();   // ONLY barrier: init visibility (all 16 waves, at top)

    if (wave == 0) {
        // publish own f0 word (tag 1, slot 0), then poll IMMEDIATELY —
        // f0 stash overlaps peers' extraction.
        {
            float f = (lane < 32) ? f0[bid * 32 + lane] : 0.0f;
            u64 m = __ballot(f != 0.0f);
            if (lane == 0)
                pub_store(&fdata[(size_t)bid * MBSTRIDE],
                          (1ull << 32) | (u32)(m & 0xffffffffull));
        }
        // ===== PURE POLLER (R13 verbatim): fresh-check, stash, backoff =====
        for (int s = 0; s < STEPS; ++s) {
            const u64* slot = fdata + (size_t)(s & 1) * CBLOCKS * MBSTRIDE;
            const u32 want = (u32)(s + 1);
            u32* fb = lds_fbits[s & 1];
            u32 pend = 0xFu;                 // 4 words per lane outstanding
            for (;;) {
                #pragma unroll
                for (int k = 0; k < 4; ++k) {
                    if ((pend >> k) & 1u) {
                        u64 w = pub_load(&slot[(size_t)(lane + 64 * k) * MBSTRIDE]);
                        if ((u32)(w >> 32) == want) {
                            fb[lane + 64 * k] = (u32)w;   // stash on arrival
                            pend &= ~(1u << k);
                        }
                    }
                }
                if (__all(pend == 0)) break;
                __builtin_amdgcn_s_sleep(2);   // ~128 cyc: cut L3 read pressure
            }
            if (lane == 0)
                __hip_atomic_store(&lds_flag, s + 1, __ATOMIC_RELEASE,
                                   __HIP_MEMORY_SCOPE_WORKGROUP);
        }
        return;
    }

    // ===== Phase 0: waves 1..15 extract 64 half-rows -> LDS ELL ===========
    // (batched-ballot compaction, R21 body verbatim; 4.27 hr/wave serial)
    {
        const u64 lmask = (1ull << lane) - 1ull;
        for (int hr = wave - 1; hr < 2 * LROWS; hr += XWAVES) {
            const int rloc = hr >> 1;
            const int half = hr & 1;
            const int cbase = half * (NN / 2);
            const float4* wr4 = (const float4*)
                (W + (size_t)(bid * LROWS + rloc) * NN + cbase);
            u64* pr = lds_ell + rloc * LPITCH + half * K_SEG;

            float4 wv[16];
            #pragma unroll
            for (int i = 0; i < 16; ++i)
                wv[i] = wr4[lane + 64 * i];

            int base = 0;
            #pragma unroll
            for (int i = 0; i < 16; ++i) {
                const int col0 = cbase + (lane + 64 * i) * 4;
                const float4 w = wv[i];
                u64 m0 = __ballot(w.x != 0.0f);
                u64 m1 = __ballot(w.y != 0.0f);
                u64 m2 = __ballot(w.z != 0.0f);
                u64 m3 = __ballot(w.w != 0.0f);
                int p0 = __popcll(m0), p1 = __popcll(m1),
                    p2 = __popcll(m2), p3 = __popcll(m3);
                int i0 = base + __popcll(m0 & lmask);
                int i1 = base + p0 + __popcll(m1 & lmask);
                int i2 = base + p0 + p1 + __popcll(m2 & lmask);
                int i3 = base + p0 + p1 + p2 + __popcll(m3 & lmask);
                if (w.x != 0.0f && i0 < K_SEG)       // +5.6 sigma guard
                    pr[i0] = ((u64)(u32)(col0 + 0) << 32)
                           | (u64)__float_as_uint(w.x);
                if (w.y != 0.0f && i1 < K_SEG)
                    pr[i1] = ((u64)(u32)(col0 + 1) << 32)
                           | (u64)__float_as_uint(w.y);
                if (w.z != 0.0f && i2 < K_SEG)
                    pr[i2] = ((u64)(u32)(col0 + 2) << 32)
                           | (u64)__float_as_uint(w.z);
                if (w.w != 0.0f && i3 < K_SEG)
                    pr[i3] = ((u64)(u32)(col0 + 3) << 32)
                           | (u64)__float_as_uint(w.w);
                base += p0 + p1 + p2 + p3;           // ONE serial update/float4
            }
            const int cap = (base < K_SEG) ? base : K_SEG;
            for (int j = cap + lane; j < K_SEG; j += 64) pr[j] = 0ull;
        }
        // release own ELL writes; signal done
        if (lane == 0)
            __hip_atomic_fetch_add(&lds_ext, 1, __ATOMIC_ACQ_REL,
                                   __HIP_MEMORY_SCOPE_WORKGROUP);
    }
    if (wave > 8) return;                    // helper waves exit (no barriers
                                             // exist past this point)

    // ===== COMPUTE (waves 1..8, 4 rows each); last wave publishes =========
    {
        const int g    = wave - 1;               // 0..7
        const int rloc = g * 4 + (lane >> 4);    // local row 0..31
        const int row  = bid * LROWS + rloc;
        const int l16  = lane & 15;

        // wait for ALL extraction waves (foreign rows), acquire their writes
        while (__hip_atomic_load(&lds_ext, __ATOMIC_ACQUIRE,
                                 __HIP_MEMORY_SCOPE_WORKGROUP) < XWAVES) {}

        // one-time LDS ELL -> registers
        u32 ecol[KITER]; float eval[KITER];
        const u64* pr = lds_ell + rloc * LPITCH;
        #pragma unroll
        for (int k = 0; k < KITER; ++k) {
            u64 p = pr[l16 + 16 * k];
            ecol[k] = (u32)(p >> 32);
            eval[k] = __uint_as_float((u32)p);
        }
        float vreg = v0[row];                    // identical across the 16 lanes

        for (int s = 0; s < STEPS; ++s) {
            while (__hip_atomic_load(&lds_flag, __ATOMIC_ACQUIRE,
                                     __HIP_MEMORY_SCOPE_WORKGROUP) < s + 1) {}
            const u32* fb = lds_fbits[s & 1];

            // gather with 3 independent fp64 accumulators (short dep chains)
            double a0 = 0.0, a1 = 0.0, a2 = 0.0;
            #pragma unroll
            for (int k = 0; k < KITER; k += 3) {
                u32 c0 = ecol[k],     w0 = fb[c0 >> 5];
                u32 c1 = ecol[k + 1], w1 = fb[c1 >> 5];
                u32 c2 = ecol[k + 2], w2 = fb[c2 >> 5];
                a0 += (double)(((w0 >> (c0 & 31)) & 1u) ? eval[k]     : 0.0f);
                a1 += (double)(((w1 >> (c1 & 31)) & 1u) ? eval[k + 1] : 0.0f);
                a2 += (double)(((w2 >> (c2 & 31)) & 1u) ? eval[k + 2] : 0.0f);
            }
            double acc = (a0 + a1) + a2;
            #pragma unroll
            for (int m = 8; m >= 1; m >>= 1)     // 16-lane butterfly
                acc += __shfl_xor(acc, m, 64);

            float u  = (float)acc;
            float vv = __fadd_rn(__fmul_rn(DECAYF, vreg), u);
            int fire = (vv >= THRESHF);
            vreg = fire ? 0.0f : vv;

            // ---- publish path FIRST (critical chain), out[] store after ----
            u64 bal = __ballot(fire);            // uniform within 16-lane groups
            int old = -1;
            if (lane == 0) {
                u32 bits4 = ((u32)(bal       ) & 1u)
                          | (((u32)(bal >> 16) & 1u) << 1)
                          | (((u32)(bal >> 32) & 1u) << 2)
                          | (((u32)(bal >> 48) & 1u) << 3);
                __hip_atomic_store(&lds_spike[g], bits4, __ATOMIC_RELAXED,
                                   __HIP_MEMORY_SCOPE_WORKGROUP);
                old = __hip_atomic_fetch_add(&lds_cnt[s], 1, __ATOMIC_ACQ_REL,
                                             __HIP_MEMORY_SCOPE_WORKGROUP);
            }
            old = __shfl(old, 0, 64);
            if (old == 7) {                      // 8th (last) compute wave
                u32 b = (lane < 8) ? ((lds_spike[lane] & 0xFu) << (4 * lane)) : 0u;
                b |= __shfl_xor(b, 1, 64);
                b |= __shfl_xor(b, 2, 64);
                b |= __shfl_xor(b, 4, 64);
                if (lane == 0)
                    pub_store(&fdata[((size_t)((s + 1) & 1) * CBLOCKS + bid) * MBSTRIDE],
                              ((u64)(u32)(s + 2) << 32) | b);
            }

            if (l16 == 0)
                out[(size_t)s * NN + row] = fire ? 1.0f : 0.0f;
        }
    }
}

extern "C" void kernel_launch(void* const* d_in, const int* in_sizes, int n_in,
                              void* d_out, int out_size, void* d_ws, size_t ws_size,
                              hipStream_t stream) {
    const float* W  = (const float*)d_in[0];
    const float* f0 = (const float*)d_in[1];
    const float* v0 = (const float*)d_in[2];
    float* out = (float*)d_out;

    // workspace: padded mailbox (64 KB); 0xAA poison != any tag 1..66
    u64* fdata = (u64*)d_ws;

    spiking_fused<<<dim3(CBLOCKS), dim3(STHREADS), 0, stream>>>(
        W, f0, v0, out, fdata);
}